// Round 1
// baseline (4488.588 us; speedup 1.0000x reference)
//
#include <hip/hip_runtime.h>
#include <hip/hip_bf16.h>

// RecognitionODEGRU — MI355X baseline: bf16-MFMA GEMM phase kernels driven as a
// ~418-launch sequence (graph-captured by the harness). fp32 state (h, kacc),
// bf16 GEMM operands, fp32 accumulation.
//
// Shapes: B=512, T=8, D=512, H=512, LAT=64, NSTEPS=4.
// d_in: 0=x(512,8,512) 1=ts(512,8) 2=Wih(1536,512) 3=Whh(1536,512) 4=bih 5=bhh
//       6=Wout(128,512) 7=bout 8=W1(1024,513) 9=b1 10=W2(1024,1024) 11=b2
//       12=W3(512,1024) 13=b3
// d_out: outs[-1] (512,128) | h (512,512) | c=zeros (512,512), all f32.

#define B_ 512
#define T_ 8
#define D_ 512
#define H_ 512
#define NSTEPS_ 4
#define WLD 576  // w-buffer width: 512 h-cols + t col (512) + zero pad → K%64==0

typedef short short8 __attribute__((ext_vector_type(8)));
typedef float f32x4 __attribute__((ext_vector_type(4)));

#define MODE_SWISH 0
#define MODE_F32   1
#define MODE_RK4   2

__device__ __forceinline__ float sigm(float x) { return 1.f / (1.f + __expf(-x)); }

// C = act(A @ W^T + bias). A: (M,K) bf16 row-major (lda), W: (N,K) bf16 row-major (ldw).
// Tile 32x64, 256 threads (4 waves; 2x2 wave grid; each wave two 16x16 MFMA tiles).
// LDS rows padded to 72 elems: b128 frag reads alias only 2-way (free on gfx950).
template <int MODE>
__global__ __launch_bounds__(256) void gemm_k(
    const __hip_bfloat16* __restrict__ A, int lda,
    const __hip_bfloat16* __restrict__ W, int ldw,
    const float* __restrict__ bias,
    float* __restrict__ outf, __hip_bfloat16* __restrict__ outb, int ldo,
    int K,
    float* __restrict__ hbuf, float* __restrict__ kaccb,
    __hip_bfloat16* __restrict__ wbuf,
    const float* __restrict__ dtbuf, const float* __restrict__ t0buf,
    int eidx, int substep)
{
  __shared__ __align__(16) __hip_bfloat16 At[32][72];
  __shared__ __align__(16) __hip_bfloat16 Bt[64][72];
  const int tid = threadIdx.x;
  const int m0 = blockIdx.y * 32, n0 = blockIdx.x * 64;
  const int lane = tid & 63, wv = tid >> 6;
  const int wm = wv & 1, wn = wv >> 1;
  const int fr = lane & 15, fk = (lane >> 4) * 8;  // A: m=lane&15, k=quad*8+j ; B: n=lane&15
  f32x4 acc0 = {0.f, 0.f, 0.f, 0.f}, acc1 = {0.f, 0.f, 0.f, 0.f};
  const int ar = tid >> 3, ac = (tid & 7) * 8;     // A stage: 32 rows x 64 cols, 16B/thread
  const int br = tid >> 2, bc = (tid & 3) * 8;     // B stage: 64 rows x 64 cols, 2x16B/thread
  const __hip_bfloat16* Arow = A + (size_t)(m0 + ar) * lda + ac;
  const __hip_bfloat16* Brow = W + (size_t)(n0 + br) * ldw + bc;

  for (int kb = 0; kb < K; kb += 64) {
    *(short8*)&At[ar][ac]      = *(const short8*)(Arow + kb);
    *(short8*)&Bt[br][bc]      = *(const short8*)(Brow + kb);
    *(short8*)&Bt[br][bc + 32] = *(const short8*)(Brow + kb + 32);
    __syncthreads();
#pragma unroll
    for (int k0 = 0; k0 < 64; k0 += 32) {
      short8 af  = *(const short8*)&At[wm * 16 + fr][k0 + fk];
      short8 bf0 = *(const short8*)&Bt[wn * 32 + fr][k0 + fk];
      short8 bf1 = *(const short8*)&Bt[wn * 32 + 16 + fr][k0 + fk];
      acc0 = __builtin_amdgcn_mfma_f32_16x16x32_bf16(af, bf0, acc0, 0, 0, 0);
      acc1 = __builtin_amdgcn_mfma_f32_16x16x32_bf16(af, bf1, acc1, 0, 0, 0);
    }
    __syncthreads();
  }

  // C/D layout (m89-verified): col = lane&15, row = (lane>>4)*4 + reg.
  const int rbase = m0 + wm * 16 + (lane >> 4) * 4;
#pragma unroll
  for (int tile = 0; tile < 2; ++tile) {
    f32x4 av = tile ? acc1 : acc0;
    const int col = n0 + wn * 32 + tile * 16 + fr;
    const float bv = bias[col];
#pragma unroll
    for (int i = 0; i < 4; ++i) {
      const int row = rbase + i;
      float v = av[i] + bv;
      if (MODE == MODE_SWISH) {
        outb[(size_t)row * ldo + col] = __float2bfloat16(v * sigm(v));
      } else if (MODE == MODE_F32) {
        outf[(size_t)row * ldo + col] = v;
      } else {  // RK4: v = k_e[row][col]; update kacc / h / next eval input w
        const int hi = row * H_ + col;
        const float dt = dtbuf[row];
        const float ka = (eidx == 1) ? v : kaccb[hi] + ((eidx == 4) ? 1.f : 2.f) * v;
        if (eidx < 4) {
          kaccb[hi] = ka;
          const float amul = (eidx == 3) ? 1.f : 0.5f;  // RK4 input coefs: 1/2, 1/2, 1
          wbuf[row * WLD + col] = __float2bfloat16(hbuf[hi] + amul * dt * v);
        } else {
          const float hn = hbuf[hi] + dt * (1.f / 6.f) * ka;  // ka = k1+2k2+2k3+k4
          hbuf[hi] = hn;
          wbuf[row * WLD + col] = __float2bfloat16(hn);
        }
      }
    }
  }
  // t column (col 512 of w) for the NEXT eval's odefunc input.
  if (MODE == MODE_RK4 && blockIdx.x == 0 && tid < 32) {
    const int r = m0 + tid;
    const float dt = dtbuf[r];
    const float ce = (eidx <= 2) ? ((float)substep + 0.5f) : ((float)substep + 1.f);
    wbuf[r * WLD + 512] = __float2bfloat16(t0buf[r] + dt * ce);
  }
}

// fp32 -> bf16 with zero-padding of K dimension (kin -> kout).
__global__ void conv_k(const float* __restrict__ in, __hip_bfloat16* __restrict__ out,
                       int rows, int kin, int kout)
{
  int idx = blockIdx.x * 256 + threadIdx.x;
  if (idx >= rows * kout) return;
  int r = idx / kout, k = idx - r * kout;
  out[idx] = __float2bfloat16(k < kin ? in[r * kin + k] : 0.f);
}

// Zero h, build initial w = [h=0 ; t=ts[:,0] ; pad=0], t0 = ts[:,0], dt = 0 (step 0 has t1==t0).
__global__ void init_k(__hip_bfloat16* __restrict__ wbuf, float* __restrict__ hbuf,
                       float* __restrict__ t0buf, float* __restrict__ dtbuf,
                       const float* __restrict__ ts)
{
  int idx = blockIdx.x * 256 + threadIdx.x;
  if (idx >= B_ * WLD) return;
  int r = idx / WLD, c = idx - r * WLD;
  float v = (c == 512) ? ts[r * T_] : 0.f;
  wbuf[idx] = __float2bfloat16(v);
  if (c < H_) hbuf[r * H_ + c] = 0.f;
  if (c == 0) { t0buf[r] = ts[r * T_]; dtbuf[r] = 0.f; }
}

// GRU gate combine: h' = (1-z)*n + z*h, then prep next step's w / t0 / dt.
__global__ void gates_k(float* __restrict__ hbuf, __hip_bfloat16* __restrict__ wbuf,
                        const float* __restrict__ gi, const float* __restrict__ gh,
                        const float* __restrict__ ts, int s,
                        float* __restrict__ t0buf, float* __restrict__ dtbuf)
{
  int idx = blockIdx.x * 256 + threadIdx.x;  // B_*H_ threads
  int r = idx >> 9, c = idx & (H_ - 1);
  const int gb = r * 3 * H_;
  float ir = gi[gb + c], iz = gi[gb + H_ + c], inn = gi[gb + 2 * H_ + c];
  float hr = gh[gb + c], hz = gh[gb + H_ + c], hn = gh[gb + 2 * H_ + c];
  float rg = sigm(ir + hr);
  float zg = sigm(iz + hz);
  float ng = tanhf(inn + rg * hn);
  float hv = (1.f - zg) * ng + zg * hbuf[idx];
  hbuf[idx] = hv;
  wbuf[r * WLD + c] = __float2bfloat16(hv);
  if (c == 0) {
    float t0n = ts[r * T_ + s];
    float t1 = (s < T_ - 1) ? ts[r * T_ + s + 1] : t0n;
    t0buf[r] = t0n;
    dtbuf[r] = (t1 - t0n) * 0.25f;
    wbuf[r * WLD + 512] = __float2bfloat16(t0n);
  }
}

// d_out tail: h (f32, full precision) and c = zeros.
__global__ void final_k(float* __restrict__ dout, const float* __restrict__ hbuf)
{
  int idx = blockIdx.x * 256 + threadIdx.x;  // B_*H_
  dout[B_ * 128 + idx] = hbuf[idx];
  dout[B_ * 128 + B_ * H_ + idx] = 0.f;
}

extern "C" void kernel_launch(void* const* d_in, const int* in_sizes, int n_in,
                              void* d_out, int out_size, void* d_ws, size_t ws_size,
                              hipStream_t stream)
{
  const float* x    = (const float*)d_in[0];
  const float* ts   = (const float*)d_in[1];
  const float* Wih  = (const float*)d_in[2];
  const float* Whh  = (const float*)d_in[3];
  const float* bih  = (const float*)d_in[4];
  const float* bhh  = (const float*)d_in[5];
  const float* Wout = (const float*)d_in[6];
  const float* bout = (const float*)d_in[7];
  const float* W1   = (const float*)d_in[8];
  const float* b1   = (const float*)d_in[9];
  const float* W2   = (const float*)d_in[10];
  const float* b2   = (const float*)d_in[11];
  const float* W3   = (const float*)d_in[12];
  const float* b3   = (const float*)d_in[13];

  char* ws = (char*)d_ws;
  size_t off = 0;
  auto alloc = [&](size_t n) { void* p = ws + off; off += (n + 255) & ~(size_t)255; return p; };

  __hip_bfloat16* xbf   = (__hip_bfloat16*)alloc((size_t)B_ * T_ * D_ * 2);
  __hip_bfloat16* Wihb  = (__hip_bfloat16*)alloc((size_t)3 * H_ * D_ * 2);
  __hip_bfloat16* Whhb  = (__hip_bfloat16*)alloc((size_t)3 * H_ * H_ * 2);
  __hip_bfloat16* W1p   = (__hip_bfloat16*)alloc((size_t)1024 * WLD * 2);
  __hip_bfloat16* W2b   = (__hip_bfloat16*)alloc((size_t)1024 * 1024 * 2);
  __hip_bfloat16* W3b   = (__hip_bfloat16*)alloc((size_t)H_ * 1024 * 2);
  __hip_bfloat16* Woutb = (__hip_bfloat16*)alloc((size_t)128 * H_ * 2);
  __hip_bfloat16* wbuf  = (__hip_bfloat16*)alloc((size_t)B_ * WLD * 2);
  __hip_bfloat16* z1    = (__hip_bfloat16*)alloc((size_t)B_ * 1024 * 2);
  __hip_bfloat16* z2    = (__hip_bfloat16*)alloc((size_t)B_ * 1024 * 2);
  float* hbuf  = (float*)alloc((size_t)B_ * H_ * 4);
  float* kaccb = (float*)alloc((size_t)B_ * H_ * 4);
  float* gi    = (float*)alloc((size_t)B_ * 3 * H_ * 4);
  float* gh    = (float*)alloc((size_t)B_ * 3 * H_ * 4);
  float* t0b   = (float*)alloc((size_t)B_ * 4);
  float* dtb   = (float*)alloc((size_t)B_ * 4);

  auto conv = [&](const float* in, __hip_bfloat16* out, int rows, int kin, int kout) {
    int n = rows * kout;
    conv_k<<<(n + 255) / 256, 256, 0, stream>>>(in, out, rows, kin, kout);
  };
  conv(x, xbf, B_ * T_, D_, D_);
  conv(Wih, Wihb, 3 * H_, D_, D_);
  conv(Whh, Whhb, 3 * H_, H_, H_);
  conv(W1, W1p, 1024, 513, WLD);
  conv(W2, W2b, 1024, 1024, 1024);
  conv(W3, W3b, 512, 1024, 1024);
  conv(Wout, Woutb, 128, H_, H_);
  init_k<<<(B_ * WLD + 255) / 256, 256, 0, stream>>>(wbuf, hbuf, t0b, dtb, ts);

  auto gemm = [&](int mode, const __hip_bfloat16* A, int lda,
                  const __hip_bfloat16* W, int ldw, const float* bias,
                  float* outf, __hip_bfloat16* outb, int ldo,
                  int M, int N, int K, int eidx, int substep) {
    dim3 g(N / 64, M / 32);
    if (mode == MODE_SWISH)
      gemm_k<MODE_SWISH><<<g, 256, 0, stream>>>(A, lda, W, ldw, bias, outf, outb, ldo, K,
                                                hbuf, kaccb, wbuf, dtb, t0b, eidx, substep);
    else if (mode == MODE_F32)
      gemm_k<MODE_F32><<<g, 256, 0, stream>>>(A, lda, W, ldw, bias, outf, outb, ldo, K,
                                              hbuf, kaccb, wbuf, dtb, t0b, eidx, substep);
    else
      gemm_k<MODE_RK4><<<g, 256, 0, stream>>>(A, lda, W, ldw, bias, outf, outb, ldo, K,
                                              hbuf, kaccb, wbuf, dtb, t0b, eidx, substep);
  };

  for (int s = 0; s < T_; ++s) {
    // gi = x[:,s,:] @ Wih^T + bih   (f32 out)
    gemm(MODE_F32, xbf + s * D_, T_ * D_, Wihb, D_, bih, gi, nullptr, 3 * H_,
         B_, 3 * H_, D_, 0, 0);
    for (int n = 0; n < NSTEPS_; ++n) {
      for (int e = 1; e <= 4; ++e) {
        // z1 = swish([w,t] @ W1^T + b1)  (K padded 513->576 with zeros)
        gemm(MODE_SWISH, wbuf, WLD, W1p, WLD, b1, nullptr, z1, 1024, B_, 1024, WLD, 0, 0);
        // z2 = swish(z1 @ W2^T + b2)
        gemm(MODE_SWISH, z1, 1024, W2b, 1024, b2, nullptr, z2, 1024, B_, 1024, 1024, 0, 0);
        // k_e = z2 @ W3^T + b3 ; fused RK4 state update + next w
        gemm(MODE_RK4, z2, 1024, W3b, 1024, b3, nullptr, nullptr, 0, B_, H_, 1024, e, n);
      }
    }
    // gh = h_ode @ Whh^T + bhh (w holds bf16(h_ode) in cols 0..511)
    gemm(MODE_F32, wbuf, WLD, Whhb, H_, bhh, gh, nullptr, 3 * H_, B_, 3 * H_, H_, 0, 0);
    gates_k<<<(B_ * H_) / 256, 256, 0, stream>>>(hbuf, wbuf, gi, gh, ts, s, t0b, dtb);
  }
  // outs[-1] = h' @ Wout^T + bout -> d_out[0 : 512*128]
  gemm(MODE_F32, wbuf, WLD, Woutb, H_, bout, (float*)d_out, nullptr, 128, B_, 128, H_, 0, 0);
  final_k<<<(B_ * H_) / 256, 256, 0, stream>>>((float*)d_out, hbuf);
}

// Round 2
// 4053.972 us; speedup vs baseline: 1.1072x; 1.1072x over previous
//
#include <hip/hip_runtime.h>
#include <hip/hip_bf16.h>

// RecognitionODEGRU R1 — async double-buffered bf16-MFMA GEMM phases.
// Changes vs R0: global_load_lds(16B) staging + XOR-swizzled LDS (no pad),
// LDS double-buffer (1 barrier/K-iter, loads overlap compute), batched gi GEMM
// (4096x1536x512 once instead of 8x), layer-1 t-column folded into rank-1
// epilogue term (K 576->512).
//
// Shapes: B=512, T=8, D=512, H=512, LAT=64, NSTEPS=4.
// d_out: outs[-1] (512,128) | h (512,512) | c=zeros (512,512), f32.

#define B_ 512
#define T_ 8
#define D_ 512
#define H_ 512
#define NSTEPS_ 4

typedef short short8 __attribute__((ext_vector_type(8)));
typedef float f32x4 __attribute__((ext_vector_type(4)));

#define MODE_SWISH1 0  // z1 = swish(acc + b1 + tcur[row]*w1t[col]) -> bf16
#define MODE_SWISH  1  // z2 = swish(acc + bias) -> bf16
#define MODE_F32    2  // out = acc + bias -> f32
#define MODE_RK4    3  // k_e = acc + bias; fused RK4 state update

__device__ __forceinline__ float sigm(float x) { return 1.f / (1.f + __expf(-x)); }

__device__ __forceinline__ void async_cp16(const __hip_bfloat16* g, __hip_bfloat16* l) {
  __builtin_amdgcn_global_load_lds(
      (const __attribute__((address_space(1))) void*)g,
      (__attribute__((address_space(3))) void*)l, 16, 0, 0);
}

// C = act(A @ W^T + bias). A:(M,K) bf16 rm (lda), W:(N,K) bf16 rm (ldw).
// Block tile 32x64, 256 threads, 2x2 waves, wave = two 16x16x32 MFMA tiles.
// LDS: 16B-granule XOR swizzle slot(r,c8)=r*8+(c8^(r&7)) — conflict-aliasing
// is 2-way only (free), and layout is global_load_lds-compatible (no pad).
template <int MODE>
__global__ __launch_bounds__(256) void gemm_k(
    const __hip_bfloat16* __restrict__ A, int lda,
    const __hip_bfloat16* __restrict__ W, int ldw,
    const float* __restrict__ bias,
    float* __restrict__ outf, __hip_bfloat16* __restrict__ outb, int ldo,
    int K,
    float* __restrict__ hbuf, float* __restrict__ kaccb,
    __hip_bfloat16* __restrict__ wbuf,
    const float* __restrict__ dtbuf, const float* __restrict__ t0buf,
    float* __restrict__ tcur, const float* __restrict__ w1t,
    int eidx, int substep)
{
  __shared__ __align__(16) __hip_bfloat16 sA[2][32 * 64];
  __shared__ __align__(16) __hip_bfloat16 sB[2][64 * 64];
  const int tid = threadIdx.x;
  const int m0 = blockIdx.y * 32, n0 = blockIdx.x * 64;
  const int lane = tid & 63, wv = tid >> 6;
  const int wm = wv & 1, wn = wv >> 1;
  const int fr = lane & 15, quad = lane >> 4;
  f32x4 acc0 = {0.f, 0.f, 0.f, 0.f}, acc1 = {0.f, 0.f, 0.f, 0.f};

  // Staging: A tile 32x64 = 256 16B slots (1/thread); B tile 64x64 = 512 (2/thread).
  // Thread's slot s: row r=s>>3, part p=s&7; global col-granule cg = p ^ (r&7).
  const int ar = tid >> 3, ap = tid & 7;
  const __hip_bfloat16* aptr = A + (size_t)(m0 + ar) * lda + (size_t)((ap ^ (ar & 7)) * 8);
  const __hip_bfloat16* bptr0 = W + (size_t)(n0 + ar) * ldw + (size_t)((ap ^ (ar & 7)) * 8);
  const __hip_bfloat16* bptr1 = bptr0 + (size_t)32 * ldw;  // (r+32)&7 == r&7 -> same cg
  __hip_bfloat16* lA = &sA[0][0] + wv * 512;        // wave-uniform base, +lane*16B by HW
  __hip_bfloat16* lB0 = &sB[0][0] + wv * 512;
  __hip_bfloat16* lB1 = &sB[0][0] + 2048 + wv * 512;
  const int bufstrideA = 32 * 64, bufstrideB = 64 * 64;

  // Fragment LDS addressing (elems): A row arow, k-granule g -> slot arow*8+(g^(arow&7)).
  const int arow = wm * 16 + fr;
  const int abase = arow * 8, asw = arow & 7;
  const int brow0 = wn * 32 + fr, brow1 = brow0 + 16;     // brow1&7 == brow0&7
  const int bbase0 = brow0 * 8, bbase1 = brow1 * 8, bsw = brow0 & 7;

  auto stage = [&](int kb, int buf) {
    async_cp16(aptr + kb, lA + buf * bufstrideA);
    async_cp16(bptr0 + kb, lB0 + buf * bufstrideB);
    async_cp16(bptr1 + kb, lB1 + buf * bufstrideB);
  };

  stage(0, 0);
  __syncthreads();  // drains vmcnt -> tile 0 resident
  const int nk = K >> 6;
  for (int i = 0; i < nk; ++i) {
    const int buf = i & 1;
    if (i + 1 < nk) stage((i + 1) << 6, buf ^ 1);  // overlap with compute below
#pragma unroll
    for (int k0 = 0; k0 < 64; k0 += 32) {
      const int g = (k0 >> 3) + quad;
      short8 af = *(const short8*)&sA[buf][(abase + (g ^ asw)) * 8];
      short8 b0 = *(const short8*)&sB[buf][(bbase0 + (g ^ bsw)) * 8];
      short8 b1 = *(const short8*)&sB[buf][(bbase1 + (g ^ bsw)) * 8];
      acc0 = __builtin_amdgcn_mfma_f32_16x16x32_bf16(af, b0, acc0, 0, 0, 0);
      acc1 = __builtin_amdgcn_mfma_f32_16x16x32_bf16(af, b1, acc1, 0, 0, 0);
    }
    __syncthreads();  // loads for i+1 done; all waves done reading buf
  }

  // C/D: col = lane&15, row = quad*4 + reg (m89-verified).
  const int rbase = m0 + wm * 16 + quad * 4;
#pragma unroll
  for (int tile = 0; tile < 2; ++tile) {
    f32x4 av = tile ? acc1 : acc0;
    const int col = n0 + wn * 32 + tile * 16 + fr;
    const float bv = bias[col];
#pragma unroll
    for (int i = 0; i < 4; ++i) {
      const int row = rbase + i;
      float v = av[i] + bv;
      if (MODE == MODE_SWISH1) {
        v += tcur[row] * w1t[col];
        outb[(size_t)row * ldo + col] = __float2bfloat16(v * sigm(v));
      } else if (MODE == MODE_SWISH) {
        outb[(size_t)row * ldo + col] = __float2bfloat16(v * sigm(v));
      } else if (MODE == MODE_F32) {
        outf[(size_t)row * ldo + col] = v;
      } else {  // RK4
        const int hi = row * H_ + col;
        const float dt = dtbuf[row];
        const float ka = (eidx == 1) ? v : kaccb[hi] + ((eidx == 4) ? 1.f : 2.f) * v;
        if (eidx < 4) {
          kaccb[hi] = ka;
          const float amul = (eidx == 3) ? 1.f : 0.5f;
          wbuf[row * H_ + col] = __float2bfloat16(hbuf[hi] + amul * dt * v);
        } else {
          const float hn = hbuf[hi] + dt * (1.f / 6.f) * ka;
          hbuf[hi] = hn;
          wbuf[row * H_ + col] = __float2bfloat16(hn);
        }
      }
    }
  }
  // Advance tcur (f32) for the next eval's t.
  if (MODE == MODE_RK4 && blockIdx.x == 0 && tid < 32) {
    const int r = m0 + tid;
    const float ce = (eidx <= 2) ? ((float)substep + 0.5f) : ((float)substep + 1.f);
    tcur[r] = t0buf[r] + dtbuf[r] * ce;
  }
}

// fp32 -> bf16, truncating or zero-padding K (kin -> kout).
__global__ void conv_k(const float* __restrict__ in, __hip_bfloat16* __restrict__ out,
                       int rows, int kin, int kout)
{
  int idx = blockIdx.x * 256 + threadIdx.x;
  if (idx >= rows * kout) return;
  int r = idx / kout, k = idx - r * kout;
  out[idx] = __float2bfloat16(k < kin ? in[(size_t)r * kin + k] : 0.f);
}

// w1t[i] = W1[i, 512] (f32 kept full precision for the rank-1 epilogue term).
__global__ void w1t_k(const float* __restrict__ W1, float* __restrict__ w1t)
{
  int i = blockIdx.x * 256 + threadIdx.x;
  if (i < 1024) w1t[i] = W1[(size_t)i * 513 + 512];
}

// h=0, w=bf16(0), tcur=t0=ts[:,0], dt=0 (step 0 has t1==t0).
__global__ void init_k(__hip_bfloat16* __restrict__ wbuf, float* __restrict__ hbuf,
                       float* __restrict__ t0buf, float* __restrict__ dtbuf,
                       float* __restrict__ tcur, const float* __restrict__ ts)
{
  int idx = blockIdx.x * 256 + threadIdx.x;  // B_*H_
  int r = idx >> 9;
  wbuf[idx] = __float2bfloat16(0.f);
  hbuf[idx] = 0.f;
  if ((idx & (H_ - 1)) == 0) {
    float t0 = ts[r * T_];
    t0buf[r] = t0; tcur[r] = t0; dtbuf[r] = 0.f;
  }
}

// GRU gate combine + next-step time setup. gi is batched: row (r*8+s).
__global__ void gates_k(float* __restrict__ hbuf, __hip_bfloat16* __restrict__ wbuf,
                        const float* __restrict__ gi, const float* __restrict__ gh,
                        const float* __restrict__ ts, int s,
                        float* __restrict__ t0buf, float* __restrict__ dtbuf,
                        float* __restrict__ tcur)
{
  int idx = blockIdx.x * 256 + threadIdx.x;  // B_*H_
  int r = idx >> 9, c = idx & (H_ - 1);
  const size_t gib = (size_t)((r << 3) + s) * (3 * H_);
  const size_t ghb = (size_t)r * (3 * H_);
  float ir = gi[gib + c], iz = gi[gib + H_ + c], inn = gi[gib + 2 * H_ + c];
  float hr = gh[ghb + c], hz = gh[ghb + H_ + c], hn = gh[ghb + 2 * H_ + c];
  float rg = sigm(ir + hr);
  float zg = sigm(iz + hz);
  float ng = tanhf(inn + rg * hn);
  float hv = (1.f - zg) * ng + zg * hbuf[idx];
  hbuf[idx] = hv;
  wbuf[idx] = __float2bfloat16(hv);
  if (c == 0) {
    float t0n = ts[r * T_ + s];
    float t1 = (s < T_ - 1) ? ts[r * T_ + s + 1] : t0n;
    t0buf[r] = t0n; tcur[r] = t0n;
    dtbuf[r] = (t1 - t0n) * 0.25f;
  }
}

__global__ void final_k(float* __restrict__ dout, const float* __restrict__ hbuf)
{
  int idx = blockIdx.x * 256 + threadIdx.x;  // B_*H_
  dout[B_ * 128 + idx] = hbuf[idx];
  dout[B_ * 128 + B_ * H_ + idx] = 0.f;
}

extern "C" void kernel_launch(void* const* d_in, const int* in_sizes, int n_in,
                              void* d_out, int out_size, void* d_ws, size_t ws_size,
                              hipStream_t stream)
{
  const float* x    = (const float*)d_in[0];
  const float* ts   = (const float*)d_in[1];
  const float* Wih  = (const float*)d_in[2];
  const float* Whh  = (const float*)d_in[3];
  const float* bih  = (const float*)d_in[4];
  const float* bhh  = (const float*)d_in[5];
  const float* Wout = (const float*)d_in[6];
  const float* bout = (const float*)d_in[7];
  const float* W1   = (const float*)d_in[8];
  const float* b1   = (const float*)d_in[9];
  const float* W2   = (const float*)d_in[10];
  const float* b2   = (const float*)d_in[11];
  const float* W3   = (const float*)d_in[12];
  const float* b3   = (const float*)d_in[13];

  char* ws = (char*)d_ws;
  size_t off = 0;
  auto alloc = [&](size_t n) { void* p = ws + off; off += (n + 255) & ~(size_t)255; return p; };

  __hip_bfloat16* xbf   = (__hip_bfloat16*)alloc((size_t)B_ * T_ * D_ * 2);
  __hip_bfloat16* Wihb  = (__hip_bfloat16*)alloc((size_t)3 * H_ * D_ * 2);
  __hip_bfloat16* Whhb  = (__hip_bfloat16*)alloc((size_t)3 * H_ * H_ * 2);
  __hip_bfloat16* W1hb  = (__hip_bfloat16*)alloc((size_t)1024 * 512 * 2);
  __hip_bfloat16* W2b   = (__hip_bfloat16*)alloc((size_t)1024 * 1024 * 2);
  __hip_bfloat16* W3b   = (__hip_bfloat16*)alloc((size_t)H_ * 1024 * 2);
  __hip_bfloat16* Woutb = (__hip_bfloat16*)alloc((size_t)128 * H_ * 2);
  __hip_bfloat16* wbuf  = (__hip_bfloat16*)alloc((size_t)B_ * H_ * 2);
  __hip_bfloat16* z1    = (__hip_bfloat16*)alloc((size_t)B_ * 1024 * 2);
  __hip_bfloat16* z2    = (__hip_bfloat16*)alloc((size_t)B_ * 1024 * 2);
  float* hbuf  = (float*)alloc((size_t)B_ * H_ * 4);
  float* kaccb = (float*)alloc((size_t)B_ * H_ * 4);
  float* gi    = (float*)alloc((size_t)B_ * T_ * 3 * H_ * 4);  // batched: 25 MB
  float* gh    = (float*)alloc((size_t)B_ * 3 * H_ * 4);
  float* t0b   = (float*)alloc((size_t)B_ * 4);
  float* dtb   = (float*)alloc((size_t)B_ * 4);
  float* tcur  = (float*)alloc((size_t)B_ * 4);
  float* w1t   = (float*)alloc((size_t)1024 * 4);

  auto conv = [&](const float* in, __hip_bfloat16* out, int rows, int kin, int kout) {
    int n = rows * kout;
    conv_k<<<(n + 255) / 256, 256, 0, stream>>>(in, out, rows, kin, kout);
  };
  conv(x, xbf, B_ * T_, D_, D_);
  conv(Wih, Wihb, 3 * H_, D_, D_);
  conv(Whh, Whhb, 3 * H_, H_, H_);
  conv(W1, W1hb, 1024, 513, 512);   // truncate: cols 0..511
  conv(W2, W2b, 1024, 1024, 1024);
  conv(W3, W3b, 512, 1024, 1024);
  conv(Wout, Woutb, 128, H_, H_);
  w1t_k<<<4, 256, 0, stream>>>(W1, w1t);
  init_k<<<(B_ * H_) / 256, 256, 0, stream>>>(wbuf, hbuf, t0b, dtb, tcur, ts);

  auto gemm = [&](int mode, const __hip_bfloat16* A, int lda,
                  const __hip_bfloat16* W, int ldw, const float* bias,
                  float* outf, __hip_bfloat16* outb, int ldo,
                  int M, int N, int K, int eidx, int substep) {
    dim3 g(N / 64, M / 32);
    if (mode == MODE_SWISH1)
      gemm_k<MODE_SWISH1><<<g, 256, 0, stream>>>(A, lda, W, ldw, bias, outf, outb, ldo, K,
                                                 hbuf, kaccb, wbuf, dtb, t0b, tcur, w1t, eidx, substep);
    else if (mode == MODE_SWISH)
      gemm_k<MODE_SWISH><<<g, 256, 0, stream>>>(A, lda, W, ldw, bias, outf, outb, ldo, K,
                                                hbuf, kaccb, wbuf, dtb, t0b, tcur, w1t, eidx, substep);
    else if (mode == MODE_F32)
      gemm_k<MODE_F32><<<g, 256, 0, stream>>>(A, lda, W, ldw, bias, outf, outb, ldo, K,
                                              hbuf, kaccb, wbuf, dtb, t0b, tcur, w1t, eidx, substep);
    else
      gemm_k<MODE_RK4><<<g, 256, 0, stream>>>(A, lda, W, ldw, bias, outf, outb, ldo, K,
                                              hbuf, kaccb, wbuf, dtb, t0b, tcur, w1t, eidx, substep);
  };

  // Batched gi for all steps: (B*T, 3H) = (4096,1536), K=512. 3072 blocks.
  gemm(MODE_F32, xbf, D_, Wihb, D_, bih, gi, nullptr, 3 * H_, B_ * T_, 3 * H_, D_, 0, 0);

  for (int s = 0; s < T_; ++s) {
    for (int n = 0; n < NSTEPS_; ++n) {
      for (int e = 1; e <= 4; ++e) {
        // z1 = swish(w @ W1h^T + tcur*w1t + b1), K=512
        gemm(MODE_SWISH1, wbuf, H_, W1hb, 512, b1, nullptr, z1, 1024, B_, 1024, 512, 0, 0);
        // z2 = swish(z1 @ W2^T + b2), K=1024
        gemm(MODE_SWISH, z1, 1024, W2b, 1024, b2, nullptr, z2, 1024, B_, 1024, 1024, 0, 0);
        // k_e = z2 @ W3^T + b3 ; fused RK4 update, K=1024
        gemm(MODE_RK4, z2, 1024, W3b, 1024, b3, nullptr, nullptr, 0, B_, H_, 1024, e, n);
      }
    }
    // gh = h_ode @ Whh^T + bhh
    gemm(MODE_F32, wbuf, H_, Whhb, H_, bhh, gh, nullptr, 3 * H_, B_, 3 * H_, H_, 0, 0);
    gates_k<<<(B_ * H_) / 256, 256, 0, stream>>>(hbuf, wbuf, gi, gh, ts, s, t0b, dtb, tcur);
  }
  gemm(MODE_F32, wbuf, H_, Woutb, H_, bout, (float*)d_out, nullptr, 128, B_, 128, H_, 0, 0);
  final_k<<<(B_ * H_) / 256, 256, 0, stream>>>((float*)d_out, hbuf);
}